// Round 5
// baseline (161.614 us; speedup 1.0000x reference)
//
#include <hip/hip_runtime.h>
#include <hip/hip_bf16.h>

// ListMLE: mean(cumlogsumexp(gather(outputs, labels), axis=1) - outputs)
// B=8192 rows, N=4096 cols. outputs fp32, labels int32 (per-row permutation).
// R5: persistent pipelined blocks -- each block does ROWS=4 rows; row k+1
//     outputs+labels are loaded into REGISTERS during row k's compute
//     (T14 async-STAGE split: barriers don't drain reg loads; the ds_write
//     of the prefetch regs carries the counted vmcnt wait, covered by
//     gather+scan+log work). Removes per-row cold-start load latency.

#define N_COLS 4096
#define BLOCK 256
#define PER_THREAD (N_COLS / BLOCK)  // 16
#define NWAVES (BLOCK / 64)          // 4
#define ROWS 4
#define LOG2E 1.4426950408889634f
#define LN2   0.6931471805599453f

__global__ __launch_bounds__(BLOCK, 8) void listmle_rows_kernel(
    const float* __restrict__ outputs,
    const int*   __restrict__ labels,
    double*      __restrict__ partials)
{
    __shared__ float out_lds[N_COLS];       // 16 KB row buffer
    __shared__ float wave_t[NWAVES];
    __shared__ float wpre_t[NWAVES];
    __shared__ float wsum[NWAVES];

    const int tid  = threadIdx.x;
    const int lane = tid & 63;
    const int wid  = tid >> 6;
    const size_t row0  = (size_t)blockIdx.x * ROWS;
    const int    start = tid * PER_THREAD;

    float4* o4 = (float4*)out_lds;

    // ---- prologue: load row 0 (outputs + labels) into registers ----
    float4 of0, of1, of2, of3;
    int4   lf0, lf1, lf2, lf3;
    {
        const float4* orow = (const float4*)(outputs + row0 * N_COLS);
        const int4*   lrow = (const int4*)(labels  + row0 * N_COLS + start);
        of0 = orow[tid];       of1 = orow[tid + 256];
        of2 = orow[tid + 512]; of3 = orow[tid + 768];
        lf0 = lrow[0]; lf1 = lrow[1]; lf2 = lrow[2]; lf3 = lrow[3];
    }
    o4[tid] = of0; o4[tid + 256] = of1; o4[tid + 512] = of2; o4[tid + 768] = of3;
    __syncthreads();

    float total_contrib = 0.0f;

    #pragma unroll
    for (int k = 0; k < ROWS; ++k) {
        // ---- current row labels -> static array (register-resident) ----
        int labs[PER_THREAD] = {
            lf0.x, lf0.y, lf0.z, lf0.w,
            lf1.x, lf1.y, lf1.z, lf1.w,
            lf2.x, lf2.y, lf2.z, lf2.w,
            lf3.x, lf3.y, lf3.z, lf3.w };

        // ---- gather + exp2 + thread-local prefix sums ----
        float p[PER_THREAD];
        float x_sum = 0.0f, run = 0.0f;
        #pragma unroll
        for (int j = 0; j < PER_THREAD; ++j) {
            float xv = out_lds[labs[j]];
            x_sum += xv;
            run += exp2f(xv * LOG2E);
            p[j] = run;
        }

        // ---- issue next-row loads into now-free regs (stay in flight) ----
        if (k + 1 < ROWS) {
            const float4* orow = (const float4*)(outputs + (row0 + k + 1) * N_COLS);
            const int4*   lrow = (const int4*)(labels  + (row0 + k + 1) * N_COLS + start);
            of0 = orow[tid];       of1 = orow[tid + 256];
            of2 = orow[tid + 512]; of3 = orow[tid + 768];
            lf0 = lrow[0]; lf1 = lrow[1]; lf2 = lrow[2]; lf3 = lrow[3];
        }

        // ---- wave-level inclusive scan of thread totals (plain adds) ----
        float inc = run;
        #pragma unroll
        for (int d = 1; d < 64; d <<= 1) {
            float v = __shfl_up(inc, d, 64);
            if (lane >= d) inc += v;
        }
        float excl = inc - run;

        if (lane == 63) wave_t[wid] = inc;
        __syncthreads();
        if (tid == 0) {
            float c = 0.0f;
            #pragma unroll
            for (int w = 0; w < NWAVES; ++w) { wpre_t[w] = c; c += wave_t[w]; }
        }
        __syncthreads();
        float E = wpre_t[wid] + excl;

        // ---- scores: 16 independent log2s ----
        float acc = 0.0f;
        #pragma unroll
        for (int j = 0; j < PER_THREAD; ++j)
            acc += __log2f(E + p[j]);
        total_contrib += LN2 * acc - x_sum;

        // ---- stage next row: ds_write of prefetch regs (vmcnt wait here) ----
        if (k + 1 < ROWS) {
            __syncthreads();   // everyone done reading out_lds for row k
            o4[tid] = of0; o4[tid + 256] = of1;
            o4[tid + 512] = of2; o4[tid + 768] = of3;
            __syncthreads();   // row k+1 staged
        }
    }

    // ---- block reduce total contribution, plain store per block ----
    #pragma unroll
    for (int d = 32; d > 0; d >>= 1)
        total_contrib += __shfl_down(total_contrib, d, 64);
    if (lane == 0) wsum[wid] = total_contrib;
    __syncthreads();
    if (tid == 0) {
        float tot = 0.0f;
        #pragma unroll
        for (int w = 0; w < NWAVES; ++w) tot += wsum[w];
        partials[blockIdx.x] = (double)tot;
    }
}

// One block: reduce partial doubles, write mean as float.
__global__ __launch_bounds__(BLOCK) void listmle_reduce_kernel(
    const double* __restrict__ partials,
    float* __restrict__ out,
    int nblocks,
    double inv_count)
{
    __shared__ double wtot[NWAVES];
    const int tid  = threadIdx.x;
    const int lane = tid & 63;
    const int wid  = tid >> 6;

    double sum = 0.0;
    for (int i = tid; i < nblocks; i += BLOCK)
        sum += partials[i];

    #pragma unroll
    for (int d = 32; d > 0; d >>= 1)
        sum += __shfl_down(sum, d, 64);
    if (lane == 0) wtot[wid] = sum;
    __syncthreads();
    if (tid == 0) {
        double tot = 0.0;
        #pragma unroll
        for (int w = 0; w < NWAVES; ++w) tot += wtot[w];
        out[0] = (float)(tot * inv_count);
    }
}

extern "C" void kernel_launch(void* const* d_in, const int* in_sizes, int n_in,
                              void* d_out, int out_size, void* d_ws, size_t ws_size,
                              hipStream_t stream)
{
    const float* outputs = (const float*)d_in[0];
    const int*   labels  = (const int*)d_in[1];
    float*  out = (float*)d_out;
    double* partials = (double*)d_ws;

    const int total = in_sizes[0];          // B * N
    const int B = total / N_COLS;           // 8192
    const int nblocks = B / ROWS;           // 2048

    listmle_rows_kernel<<<nblocks, BLOCK, 0, stream>>>(outputs, labels, partials);
    listmle_reduce_kernel<<<1, BLOCK, 0, stream>>>(partials, out, nblocks,
                                                   1.0 / (double)total);
}

// Round 6
// 49.215 us; speedup vs baseline: 3.2838x; 3.2838x over previous
//
#include <hip/hip_runtime.h>
#include <hip/hip_bf16.h>

// ListMLE: mean(cumlogsumexp(gather(outputs, labels), axis=1) - outputs)
// B=8192 rows, N=4096 cols. outputs fp32, labels int32 (per-row permutation).
// R6: pipelined multi-row blocks, spill-free this time.
//  - launch_bounds(256,4): 128-VGPR cap (R5 spilled at the 64 cap -> 264MB scratch writes)
//  - LDS double buffer buf[2][4096]: stage row k+1 while computing row k
//  - issue labels-then-outputs so counted vmcnt waits land at the staging ds_write
//  - mid-row barrier is lgkm-only (raw s_barrier) so prefetch loads stay in flight
//  - wave-prefix combine via broadcast wave_t reads (no tid0 serial + extra barrier)

#define N_COLS 4096
#define BLOCK 256
#define PER_THREAD (N_COLS / BLOCK)  // 16
#define NWAVES (BLOCK / 64)          // 4
#define ROWS 8
#define LOG2E 1.4426950408889634f
#define LN2   0.6931471805599453f

__global__ __launch_bounds__(BLOCK, 4) void listmle_rows_kernel(
    const float* __restrict__ outputs,
    const int*   __restrict__ labels,
    double*      __restrict__ partials)
{
    __shared__ float buf[2][N_COLS];        // 32 KB double buffer
    __shared__ float wave_t[NWAVES];
    __shared__ float wsum[NWAVES];

    const int tid  = threadIdx.x;
    const int lane = tid & 63;
    const int wid  = tid >> 6;
    const size_t row0  = (size_t)blockIdx.x * ROWS;
    const int    start = tid * PER_THREAD;

    // ---- prologue: row 0 labels+outputs to regs, stage buf[0] ----
    int4   lf0, lf1, lf2, lf3;
    float4 of0, of1, of2, of3;
    {
        const int4* lrow = (const int4*)(labels + row0 * N_COLS + start);
        lf0 = lrow[0]; lf1 = lrow[1]; lf2 = lrow[2]; lf3 = lrow[3];
        const float4* orow = (const float4*)(outputs + row0 * N_COLS);
        of0 = orow[tid];       of1 = orow[tid + 256];
        of2 = orow[tid + 512]; of3 = orow[tid + 768];
    }
    {
        float4* b0 = (float4*)buf[0];
        b0[tid] = of0; b0[tid + 256] = of1;
        b0[tid + 512] = of2; b0[tid + 768] = of3;
    }
    __syncthreads();

    float total_contrib = 0.0f;
    int cur = 0;

    for (int k = 0; k < ROWS; ++k) {
        // current row's labels -> static-indexed array (fully unrolled uses)
        int labs[PER_THREAD] = { lf0.x, lf0.y, lf0.z, lf0.w,
                                 lf1.x, lf1.y, lf1.z, lf1.w,
                                 lf2.x, lf2.y, lf2.z, lf2.w,
                                 lf3.x, lf3.y, lf3.z, lf3.w };

        // issue next-row loads: labels first, outputs second (counted waits
        // then drain outputs only at the staging ds_write below)
        if (k + 1 < ROWS) {
            const int4* lrow = (const int4*)(labels + (row0 + k + 1) * N_COLS + start);
            lf0 = lrow[0]; lf1 = lrow[1]; lf2 = lrow[2]; lf3 = lrow[3];
            const float4* orow = (const float4*)(outputs + (row0 + k + 1) * N_COLS);
            of0 = orow[tid];       of1 = orow[tid + 256];
            of2 = orow[tid + 512]; of3 = orow[tid + 768];
        }

        // gather + exp2 + thread-local prefix sums (from current buffer)
        const float* cb = buf[cur];
        float p[PER_THREAD];
        float x_sum = 0.0f, run = 0.0f;
        #pragma unroll
        for (int j = 0; j < PER_THREAD; ++j) {
            float xv = cb[labs[j]];
            x_sum += xv;
            run += exp2f(xv * LOG2E);
            p[j] = run;
        }

        // wave-level inclusive scan of thread totals
        float inc = run;
        #pragma unroll
        for (int d = 1; d < 64; d <<= 1) {
            float v = __shfl_up(inc, d, 64);
            if (lane >= d) inc += v;
        }
        float excl = inc - run;
        if (lane == 63) wave_t[wid] = inc;

        // lgkm-only barrier: do NOT drain vmcnt (next-row loads stay in flight)
        asm volatile("s_waitcnt lgkmcnt(0)" ::: "memory");
        __builtin_amdgcn_s_barrier();

        // exclusive wave prefix: broadcast reads of wave_t (wave-uniform loop)
        float E = excl;
        #pragma unroll
        for (int w = 0; w < NWAVES - 1; ++w)
            if (w < wid) E += wave_t[w];

        // scores: 16 independent log2s
        float acc = 0.0f;
        #pragma unroll
        for (int j = 0; j < PER_THREAD; ++j)
            acc += __log2f(E + p[j]);
        total_contrib += LN2 * acc - x_sum;

        // stage next row into the other buffer (compiler waits of* here,
        // ~a full row body after issue)
        if (k + 1 < ROWS) {
            float4* nb = (float4*)buf[cur ^ 1];
            nb[tid] = of0; nb[tid + 256] = of1;
            nb[tid + 512] = of2; nb[tid + 768] = of3;
        }
        __syncthreads();   // row-boundary barrier (nothing left outstanding)
        cur ^= 1;
    }

    // ---- block reduce total contribution, plain store per block ----
    #pragma unroll
    for (int d = 32; d > 0; d >>= 1)
        total_contrib += __shfl_down(total_contrib, d, 64);
    if (lane == 0) wsum[wid] = total_contrib;
    __syncthreads();
    if (tid == 0) {
        float tot = 0.0f;
        #pragma unroll
        for (int w = 0; w < NWAVES; ++w) tot += wsum[w];
        partials[blockIdx.x] = (double)tot;
    }
}

// One block: reduce partial doubles, write mean as float.
__global__ __launch_bounds__(BLOCK) void listmle_reduce_kernel(
    const double* __restrict__ partials,
    float* __restrict__ out,
    int nblocks,
    double inv_count)
{
    __shared__ double wtot[NWAVES];
    const int tid  = threadIdx.x;
    const int lane = tid & 63;
    const int wid  = tid >> 6;

    double sum = 0.0;
    for (int i = tid; i < nblocks; i += BLOCK)
        sum += partials[i];

    #pragma unroll
    for (int d = 32; d > 0; d >>= 1)
        sum += __shfl_down(sum, d, 64);
    if (lane == 0) wtot[wid] = sum;
    __syncthreads();
    if (tid == 0) {
        double tot = 0.0;
        #pragma unroll
        for (int w = 0; w < NWAVES; ++w) tot += wtot[w];
        out[0] = (float)(tot * inv_count);
    }
}

extern "C" void kernel_launch(void* const* d_in, const int* in_sizes, int n_in,
                              void* d_out, int out_size, void* d_ws, size_t ws_size,
                              hipStream_t stream)
{
    const float* outputs = (const float*)d_in[0];
    const int*   labels  = (const int*)d_in[1];
    float*  out = (float*)d_out;
    double* partials = (double*)d_ws;

    const int total = in_sizes[0];          // B * N
    const int B = total / N_COLS;           // 8192
    const int nblocks = B / ROWS;           // 1024

    listmle_rows_kernel<<<nblocks, BLOCK, 0, stream>>>(outputs, labels, partials);
    listmle_reduce_kernel<<<1, BLOCK, 0, stream>>>(partials, out, nblocks,
                                                   1.0 / (double)total);
}